// Round 1
// baseline (1027.588 us; speedup 1.0000x reference)
//
#include <hip/hip_runtime.h>
#include <hip/hip_bf16.h>

// GCN encoder: LN -> GCNConv(256->128)+ReLU -> GCNConv(128->128)+ReLU -> GCNConv(128->32)
// Baseline: fp32 everywhere, edge-parallel atomic scatter.

#define NNODES 65536
#define FIN 256
#define FH 128
#define FZ 32

// ---- degree: count incoming edges at dst ----
__global__ void deg_count_kernel(const int* __restrict__ dst, float* __restrict__ deg, int E) {
    int e = blockIdx.x * blockDim.x + threadIdx.x;
    if (e < E) atomicAdd(&deg[dst[e]], 1.0f);
}

// deg -> dis = rsqrt(deg + 1)
__global__ void dis_kernel(float* __restrict__ deg, int n) {
    int i = blockIdx.x * blockDim.x + threadIdx.x;
    if (i < n) deg[i] = rsqrtf(deg[i] + 1.0f);
}

// ---- fused LayerNorm + GEMM1: out[row, 0:128] = LN(x[row]) @ W1 ----
__global__ void ln_gemm1_kernel(const float* __restrict__ x,
                                const float* __restrict__ lnw, const float* __restrict__ lnb,
                                const float* __restrict__ W1, float* __restrict__ out) {
    __shared__ float xn[FIN];
    __shared__ float red[FIN];
    int row = blockIdx.x;
    int t = threadIdx.x;
    float v = x[(long long)row * FIN + t];
    red[t] = v;
    __syncthreads();
    for (int s = FIN / 2; s > 0; s >>= 1) {
        if (t < s) red[t] += red[t + s];
        __syncthreads();
    }
    float mu = red[0] * (1.0f / FIN);
    __syncthreads();
    float d = v - mu;
    red[t] = d * d;
    __syncthreads();
    for (int s = FIN / 2; s > 0; s >>= 1) {
        if (t < s) red[t] += red[t + s];
        __syncthreads();
    }
    float rs = rsqrtf(red[0] * (1.0f / FIN) + 1e-5f);
    xn[t] = d * rs * lnw[t] + lnb[t];
    __syncthreads();
    if (t < FH) {
        float acc = 0.0f;
#pragma unroll 8
        for (int k = 0; k < FIN; ++k) acc += xn[k] * W1[k * FH + t];
        out[(long long)row * FH + t] = acc;
    }
}

// ---- GEMM [N,128] @ [128,128]: one block (128 thr) per row ----
__global__ void gemm_h_kernel(const float* __restrict__ h, const float* __restrict__ W,
                              float* __restrict__ out) {
    __shared__ float hs[FH];
    int row = blockIdx.x;
    int t = threadIdx.x;
    hs[t] = h[(long long)row * FH + t];
    __syncthreads();
    float acc = 0.0f;
#pragma unroll 8
    for (int k = 0; k < FH; ++k) acc += hs[k] * W[k * FH + t];
    out[(long long)row * FH + t] = acc;
}

// ---- GEMM [N,128] @ [128,32]: one block (128 thr) per 4 rows ----
__global__ void gemm_z_kernel(const float* __restrict__ h, const float* __restrict__ W,
                              float* __restrict__ out) {
    __shared__ float hs[4][FH];
    int r0 = blockIdx.x * 4;
    int t = threadIdx.x;
#pragma unroll
    for (int i = 0; i < 4; ++i) hs[i][t] = h[(long long)(r0 + i) * FH + t];
    __syncthreads();
    int r = t >> 5, c = t & 31;
    float acc = 0.0f;
#pragma unroll 8
    for (int k = 0; k < FH; ++k) acc += hs[r][k] * W[k * FZ + c];
    out[(long long)(r0 + r) * FZ + c] = acc;
}

// ---- edge scatter: agg[dst] += xw[src] * dis[src]*dis[dst] ----
template <int F>
__global__ void scatter_kernel(const float* __restrict__ xw, const int* __restrict__ src,
                               const int* __restrict__ dst, const float* __restrict__ dis,
                               float* __restrict__ agg, long long total) {
    long long idx = (long long)blockIdx.x * blockDim.x + threadIdx.x;
    if (idx >= total) return;
    int e = (int)(idx / F);
    int f = (int)(idx % F);
    int s = src[e], d = dst[e];
    float nrm = dis[s] * dis[d];
    atomicAdd(&agg[(long long)d * F + f], xw[(long long)s * F + f] * nrm);
}

// ---- self-loop + bias (+ optional ReLU), in place on agg ----
template <int F, bool RELU>
__global__ void self_bias_kernel(const float* __restrict__ xw, const float* __restrict__ dis,
                                 const float* __restrict__ b, float* __restrict__ agg,
                                 long long total) {
    long long idx = (long long)blockIdx.x * blockDim.x + threadIdx.x;
    if (idx >= total) return;
    int i = (int)(idx / F);
    int f = (int)(idx % F);
    float di = dis[i];
    float v = agg[idx] + xw[idx] * di * di + b[f];
    agg[idx] = RELU ? fmaxf(v, 0.0f) : v;
}

extern "C" void kernel_launch(void* const* d_in, const int* in_sizes, int n_in,
                              void* d_out, int out_size, void* d_ws, size_t ws_size,
                              hipStream_t stream) {
    const float* x      = (const float*)d_in[0];
    const int*   ei     = (const int*)d_in[1];
    const float* lnw    = (const float*)d_in[2];
    const float* lnb    = (const float*)d_in[3];
    const float* W1     = (const float*)d_in[4];
    const float* b1     = (const float*)d_in[5];
    const float* W2     = (const float*)d_in[6];
    const float* b2     = (const float*)d_in[7];
    const float* W3     = (const float*)d_in[8];
    const float* b3     = (const float*)d_in[9];
    float* out = (float*)d_out;

    const int n = in_sizes[0] / FIN;      // 65536
    const int E = in_sizes[1] / 2;        // 524288
    const int* src = ei;
    const int* dst = ei + E;

    float* ws = (float*)d_ws;
    float* dis  = ws;                       // [n]
    float* bufA = ws + n;                   // [n*128]  xw
    float* bufB = bufA + (long long)n * FH; // [n*128]  agg / h

    // 1) degree -> dis
    hipMemsetAsync(dis, 0, (size_t)n * sizeof(float), stream);
    deg_count_kernel<<<(E + 255) / 256, 256, 0, stream>>>(dst, dis, E);
    dis_kernel<<<(n + 255) / 256, 256, 0, stream>>>(dis, n);

    // 2) conv1: LN fused GEMM -> bufA
    ln_gemm1_kernel<<<n, FIN, 0, stream>>>(x, lnw, lnb, W1, bufA);
    hipMemsetAsync(bufB, 0, (size_t)n * FH * sizeof(float), stream);
    {
        long long total = (long long)E * FH;
        scatter_kernel<FH><<<(int)((total + 255) / 256), 256, 0, stream>>>(bufA, src, dst, dis, bufB, total);
        long long tn = (long long)n * FH;
        self_bias_kernel<FH, true><<<(int)((tn + 255) / 256), 256, 0, stream>>>(bufA, dis, b1, bufB, tn);
    }

    // 3) conv2: bufB(h1) @ W2 -> bufA; agg into bufB (h1 dead after GEMM)
    gemm_h_kernel<<<n, FH, 0, stream>>>(bufB, W2, bufA);
    hipMemsetAsync(bufB, 0, (size_t)n * FH * sizeof(float), stream);
    {
        long long total = (long long)E * FH;
        scatter_kernel<FH><<<(int)((total + 255) / 256), 256, 0, stream>>>(bufA, src, dst, dis, bufB, total);
        long long tn = (long long)n * FH;
        self_bias_kernel<FH, true><<<(int)((tn + 255) / 256), 256, 0, stream>>>(bufA, dis, b2, bufB, tn);
    }

    // 4) conv3: bufB(h2) @ W3 -> bufA[0:n*32]; agg directly into d_out
    gemm_z_kernel<<<n / 4, FH, 0, stream>>>(bufB, W3, bufA);
    hipMemsetAsync(out, 0, (size_t)n * FZ * sizeof(float), stream);
    {
        long long total = (long long)E * FZ;
        scatter_kernel<FZ><<<(int)((total + 255) / 256), 256, 0, stream>>>(bufA, src, dst, dis, out, total);
        long long tn = (long long)n * FZ;
        self_bias_kernel<FZ, false><<<(int)((tn + 255) / 256), 256, 0, stream>>>(bufA, dis, b3, out, tn);
    }
}

// Round 2
// 286.734 us; speedup vs baseline: 3.5838x; 3.5838x over previous
//
#include <hip/hip_runtime.h>
#include <hip/hip_bf16.h>

#define NN 65536
#define FIN 256
#define FH 128
#define FZ 32

typedef unsigned short u16;
typedef unsigned int u32;
typedef __attribute__((ext_vector_type(4))) float f32x4;
typedef __attribute__((ext_vector_type(2))) float f32x2;
typedef __attribute__((ext_vector_type(8))) short bf16x8;
typedef __attribute__((ext_vector_type(4))) unsigned int uint4v;
typedef __attribute__((ext_vector_type(2))) unsigned int uint2v;

__device__ inline u16 f2bf(float v) {
    u32 u = __float_as_uint(v);
    u32 r = (u + 0x7fffu + ((u >> 16) & 1u)) >> 16;   // RNE
    return (u16)r;
}
__device__ inline float bf2f(u16 h) { return __uint_as_float(((u32)h) << 16); }

// ---------------- CSR build ----------------
__global__ void deg_count(const int* __restrict__ dst, int* __restrict__ deg, int E) {
    int e = blockIdx.x * 256 + threadIdx.x;
    if (e < E) atomicAdd(&deg[dst[e]], 1);
}

__global__ void partial_sum(const int* __restrict__ deg, int* __restrict__ part) {
    __shared__ int s[256];
    int t = threadIdx.x;
    s[t] = deg[blockIdx.x * 256 + t];
    __syncthreads();
    for (int o = 128; o > 0; o >>= 1) {
        if (t < o) s[t] += s[t + o];
        __syncthreads();
    }
    if (t == 0) part[blockIdx.x] = s[0];
}

__global__ void scan_part(const int* __restrict__ part, int* __restrict__ poffs) {
    __shared__ int s[256];
    int t = threadIdx.x;
    int v = part[t];
    s[t] = v;
    __syncthreads();
    for (int o = 1; o < 256; o <<= 1) {
        int add = (t >= o) ? s[t - o] : 0;
        __syncthreads();
        s[t] += add;
        __syncthreads();
    }
    poffs[t] = s[t] - v;  // exclusive
}

__global__ void scan_row(const int* __restrict__ deg, const int* __restrict__ poffs,
                         int* __restrict__ rowptr, int n) {
    __shared__ int s[256];
    int t = threadIdx.x;
    int i = blockIdx.x * 256 + t;
    int v = deg[i];
    s[t] = v;
    __syncthreads();
    for (int o = 1; o < 256; o <<= 1) {
        int add = (t >= o) ? s[t - o] : 0;
        __syncthreads();
        s[t] += add;
        __syncthreads();
    }
    int incl = s[t] + poffs[blockIdx.x];
    rowptr[i] = incl - v;
    if (i == n - 1) rowptr[n] = incl;
}

__global__ void dis_k(const int* __restrict__ deg, float* __restrict__ dis, int n) {
    int i = blockIdx.x * 256 + threadIdx.x;
    if (i < n) dis[i] = rsqrtf((float)deg[i] + 1.0f);
}

__global__ void csr_fill(const int* __restrict__ src, const int* __restrict__ dst,
                         const float* __restrict__ dis, int* __restrict__ cursor,
                         int* __restrict__ csrc, float* __restrict__ cw, int E) {
    int e = blockIdx.x * 256 + threadIdx.x;
    if (e >= E) return;
    int s = src[e], d = dst[e];
    int p = atomicAdd(&cursor[d], 1);
    csrc[p] = s;
    cw[p] = dis[s] * dis[d];
}

// ---------------- weight prep: fp32 W[K][N] -> split-bf16 Wt[N][K] ----------------
__global__ void w_prep(const float* __restrict__ W, u16* __restrict__ whi,
                       u16* __restrict__ wlo, int K, int N) {
    int idx = blockIdx.x * 256 + threadIdx.x;
    if (idx >= K * N) return;
    int k = idx / N, n = idx % N;
    float v = W[idx];
    u16 hi = f2bf(v);
    u16 lo = f2bf(v - bf2f(hi));
    whi[n * K + k] = hi;
    wlo[n * K + k] = lo;
}

// ---------------- split-bf16 MFMA GEMM, optional fused LayerNorm ----------------
// Y[M,N] = (LN? LayerNorm(X) : X)[M,K] @ W[K,N], W pre-split/transposed as Wt[N][K].
template <int K, int N, bool LN>
__global__ __launch_bounds__(256) void gemm_mfma(
    const float* __restrict__ X, const u16* __restrict__ WhiG, const u16* __restrict__ WloG,
    const float* __restrict__ lnw, const float* __restrict__ lnb, float* __restrict__ Y) {
    constexpr int WN = (N == 128) ? 2 : 1;   // waves along N
    constexpr int WM = 4 / WN;               // waves along M
    constexpr int BM = WM * 16;              // rows per block
    constexpr int NT = (N / WN) / 16;        // 16-col tiles per wave
    constexpr int KP = K + 8;                // padded LDS stride (bank spread)

    __shared__ alignas(16) u16 A_hi[BM][KP];
    __shared__ alignas(16) u16 A_lo[BM][KP];
    __shared__ alignas(16) u16 W_hi[N][40];
    __shared__ alignas(16) u16 W_lo[N][40];

    const int t = threadIdx.x;
    const int row0 = blockIdx.x * BM;

    if (LN) {
        // K==256, BM==32: 8 threads per row, 32 floats each
        const int r = t >> 3, q = t & 7;
        const float* xr = X + (long long)(row0 + r) * K + q * 32;
        float v[32];
        float s = 0.f, ss = 0.f;
#pragma unroll
        for (int j = 0; j < 8; ++j) {
            f32x4 f = *reinterpret_cast<const f32x4*>(xr + j * 4);
#pragma unroll
            for (int c = 0; c < 4; ++c) {
                float x = f[c];
                v[j * 4 + c] = x;
                s += x;
                ss += x * x;
            }
        }
#pragma unroll
        for (int m = 1; m < 8; m <<= 1) {
            s += __shfl_xor(s, m);
            ss += __shfl_xor(ss, m);
        }
        float mu = s * (1.0f / K);
        float rsig = rsqrtf(ss * (1.0f / K) - mu * mu + 1e-5f);
#pragma unroll
        for (int j4 = 0; j4 < 32; j4 += 4) {
            int k = q * 32 + j4;
            u16 h[4], lo[4];
#pragma unroll
            for (int c = 0; c < 4; ++c) {
                float xn = (v[j4 + c] - mu) * rsig * lnw[k + c] + lnb[k + c];
                h[c] = f2bf(xn);
                lo[c] = f2bf(xn - bf2f(h[c]));
            }
            uint2v H, L;
            H.x = (u32)h[0] | ((u32)h[1] << 16);
            H.y = (u32)h[2] | ((u32)h[3] << 16);
            L.x = (u32)lo[0] | ((u32)lo[1] << 16);
            L.y = (u32)lo[2] | ((u32)lo[3] << 16);
            *reinterpret_cast<uint2v*>(&A_hi[r][k]) = H;
            *reinterpret_cast<uint2v*>(&A_lo[r][k]) = L;
        }
    } else {
        for (int i = t; i < BM * (K / 4); i += 256) {
            int r = i / (K / 4);
            int k = (i % (K / 4)) * 4;
            f32x4 f = *reinterpret_cast<const f32x4*>(X + (long long)(row0 + r) * K + k);
            u16 h[4], lo[4];
#pragma unroll
            for (int c = 0; c < 4; ++c) {
                float x = f[c];
                h[c] = f2bf(x);
                lo[c] = f2bf(x - bf2f(h[c]));
            }
            uint2v H, L;
            H.x = (u32)h[0] | ((u32)h[1] << 16);
            H.y = (u32)h[2] | ((u32)h[3] << 16);
            L.x = (u32)lo[0] | ((u32)lo[1] << 16);
            L.y = (u32)lo[2] | ((u32)lo[3] << 16);
            *reinterpret_cast<uint2v*>(&A_hi[r][k]) = H;
            *reinterpret_cast<uint2v*>(&A_lo[r][k]) = L;
        }
    }

    const int wave = t >> 6, l = t & 63;
    const int wm = wave / WN, wn = wave % WN;
    const int lm = l & 15, lq = l >> 4;

    f32x4 acc[NT];
#pragma unroll
    for (int i = 0; i < NT; ++i) acc[i] = (f32x4){0.f, 0.f, 0.f, 0.f};

    for (int kk = 0; kk < K / 32; ++kk) {
        __syncthreads();
        // stage Wt slice [N][32], hi + lo
        for (int i = t; i < N * 4; i += 256) {
            int n = i >> 2, ko = (i & 3) * 8;
            uint4v vh = *reinterpret_cast<const uint4v*>(WhiG + n * K + kk * 32 + ko);
            uint4v vl = *reinterpret_cast<const uint4v*>(WloG + n * K + kk * 32 + ko);
            *reinterpret_cast<uint4v*>(&W_hi[n][ko]) = vh;
            *reinterpret_cast<uint4v*>(&W_lo[n][ko]) = vl;
        }
        __syncthreads();

        bf16x8 ah = *reinterpret_cast<const bf16x8*>(&A_hi[wm * 16 + lm][kk * 32 + lq * 8]);
        bf16x8 al = *reinterpret_cast<const bf16x8*>(&A_lo[wm * 16 + lm][kk * 32 + lq * 8]);
#pragma unroll
        for (int nt = 0; nt < NT; ++nt) {
            int n = wn * (N / WN) + nt * 16 + lm;
            bf16x8 bh = *reinterpret_cast<const bf16x8*>(&W_hi[n][lq * 8]);
            bf16x8 bl = *reinterpret_cast<const bf16x8*>(&W_lo[n][lq * 8]);
            acc[nt] = __builtin_amdgcn_mfma_f32_16x16x32_bf16(ah, bh, acc[nt], 0, 0, 0);
            acc[nt] = __builtin_amdgcn_mfma_f32_16x16x32_bf16(ah, bl, acc[nt], 0, 0, 0);
            acc[nt] = __builtin_amdgcn_mfma_f32_16x16x32_bf16(al, bh, acc[nt], 0, 0, 0);
        }
    }

    const int mbase = row0 + wm * 16 + lq * 4;
#pragma unroll
    for (int nt = 0; nt < NT; ++nt) {
        int c = wn * (N / WN) + nt * 16 + lm;
#pragma unroll
        for (int r = 0; r < 4; ++r) Y[(long long)(mbase + r) * N + c] = acc[nt][r];
    }
}

// ---------------- CSR gather aggregation, fused self-loop + bias (+ ReLU) ----------------
__global__ __launch_bounds__(256) void agg128(
    const float* __restrict__ XW, const int* __restrict__ rowptr, const int* __restrict__ csrc,
    const float* __restrict__ cw, const float* __restrict__ dis, const float* __restrict__ bias,
    float* __restrict__ OUT, int relu) {
    int node = blockIdx.x * 4 + (threadIdx.x >> 6);
    int l = threadIdx.x & 63;
    float di = dis[node];
    f32x2 b2 = *reinterpret_cast<const f32x2*>(bias + l * 2);
    f32x2 sl = *reinterpret_cast<const f32x2*>(XW + (long long)node * 128 + l * 2);
    float ax = sl.x * di * di + b2.x;
    float ay = sl.y * di * di + b2.y;
    int e = rowptr[node], e1 = rowptr[node + 1];
    for (; e + 2 <= e1; e += 2) {
        int s0 = csrc[e], s1 = csrc[e + 1];
        float w0 = cw[e], w1 = cw[e + 1];
        f32x2 v0 = *reinterpret_cast<const f32x2*>(XW + (long long)s0 * 128 + l * 2);
        f32x2 v1 = *reinterpret_cast<const f32x2*>(XW + (long long)s1 * 128 + l * 2);
        ax += v0.x * w0 + v1.x * w1;
        ay += v0.y * w0 + v1.y * w1;
    }
    if (e < e1) {
        int s0 = csrc[e];
        float w0 = cw[e];
        f32x2 v0 = *reinterpret_cast<const f32x2*>(XW + (long long)s0 * 128 + l * 2);
        ax += v0.x * w0;
        ay += v0.y * w0;
    }
    if (relu) {
        ax = fmaxf(ax, 0.f);
        ay = fmaxf(ay, 0.f);
    }
    f32x2 r;
    r.x = ax;
    r.y = ay;
    *reinterpret_cast<f32x2*>(OUT + (long long)node * 128 + l * 2) = r;
}

__global__ __launch_bounds__(256) void agg32(
    const float* __restrict__ XW, const int* __restrict__ rowptr, const int* __restrict__ csrc,
    const float* __restrict__ cw, const float* __restrict__ dis, const float* __restrict__ bias,
    float* __restrict__ OUT) {
    int node = blockIdx.x * 8 + (threadIdx.x >> 5);
    int f = threadIdx.x & 31;
    float di = dis[node];
    float acc = XW[(long long)node * 32 + f] * di * di + bias[f];
    int e = rowptr[node], e1 = rowptr[node + 1];
    for (; e + 2 <= e1; e += 2) {
        int s0 = csrc[e], s1 = csrc[e + 1];
        float w0 = cw[e], w1 = cw[e + 1];
        acc += XW[(long long)s0 * 32 + f] * w0 + XW[(long long)s1 * 32 + f] * w1;
    }
    if (e < e1) acc += XW[(long long)csrc[e] * 32 + f] * cw[e];
    OUT[(long long)node * 32 + f] = acc;
}

extern "C" void kernel_launch(void* const* d_in, const int* in_sizes, int n_in,
                              void* d_out, int out_size, void* d_ws, size_t ws_size,
                              hipStream_t stream) {
    const float* x = (const float*)d_in[0];
    const int* ei = (const int*)d_in[1];
    const float* lnw = (const float*)d_in[2];
    const float* lnb = (const float*)d_in[3];
    const float* W1 = (const float*)d_in[4];
    const float* b1 = (const float*)d_in[5];
    const float* W2 = (const float*)d_in[6];
    const float* b2 = (const float*)d_in[7];
    const float* W3 = (const float*)d_in[8];
    const float* b3 = (const float*)d_in[9];
    float* out = (float*)d_out;

    const int n = in_sizes[0] / FIN;  // 65536
    const int E = in_sizes[1] / 2;    // 524288
    const int* src = ei;
    const int* dst = ei + E;

    char* w = (char*)d_ws;
    auto alloc = [&](size_t bytes) {
        char* p = w;
        w += (bytes + 255) & ~(size_t)255;
        return p;
    };
    int* deg = (int*)alloc((size_t)n * 4);
    int* rowp = (int*)alloc((size_t)(n + 1) * 4);
    int* cur = (int*)alloc((size_t)n * 4);
    int* part = (int*)alloc(256 * 4);
    int* poffs = (int*)alloc(256 * 4);
    float* dis = (float*)alloc((size_t)n * 4);
    int* csrc = (int*)alloc((size_t)E * 4);
    float* cwt = (float*)alloc((size_t)E * 4);
    u16* w1h = (u16*)alloc(FIN * FH * 2);
    u16* w1l = (u16*)alloc(FIN * FH * 2);
    u16* w2h = (u16*)alloc(FH * FH * 2);
    u16* w2l = (u16*)alloc(FH * FH * 2);
    u16* w3h = (u16*)alloc(FH * FZ * 2);
    u16* w3l = (u16*)alloc(FH * FZ * 2);
    float* bufA = (float*)alloc((size_t)n * FH * 4);
    float* bufB = (float*)alloc((size_t)n * FH * 4);

    // ---- CSR build ----
    hipMemsetAsync(deg, 0, (size_t)n * 4, stream);
    deg_count<<<E / 256, 256, 0, stream>>>(dst, deg, E);
    partial_sum<<<n / 256, 256, 0, stream>>>(deg, part);
    scan_part<<<1, 256, 0, stream>>>(part, poffs);
    scan_row<<<n / 256, 256, 0, stream>>>(deg, poffs, rowp, n);
    dis_k<<<n / 256, 256, 0, stream>>>(deg, dis, n);
    hipMemcpyAsync(cur, rowp, (size_t)n * 4, hipMemcpyDeviceToDevice, stream);
    csr_fill<<<E / 256, 256, 0, stream>>>(src, dst, dis, cur, csrc, cwt, E);

    // ---- weight prep ----
    w_prep<<<(FIN * FH + 255) / 256, 256, 0, stream>>>(W1, w1h, w1l, FIN, FH);
    w_prep<<<(FH * FH + 255) / 256, 256, 0, stream>>>(W2, w2h, w2l, FH, FH);
    w_prep<<<(FH * FZ + 255) / 256, 256, 0, stream>>>(W3, w3h, w3l, FH, FZ);

    // ---- conv1: LN + GEMM -> gather ----
    gemm_mfma<256, 128, true><<<n / 32, 256, 0, stream>>>(x, w1h, w1l, lnw, lnb, bufA);
    agg128<<<n / 4, 256, 0, stream>>>(bufA, rowp, csrc, cwt, dis, b1, bufB, 1);

    // ---- conv2 ----
    gemm_mfma<128, 128, false><<<n / 32, 256, 0, stream>>>(bufB, w2h, w2l, nullptr, nullptr, bufA);
    agg128<<<n / 4, 256, 0, stream>>>(bufA, rowp, csrc, cwt, dis, b2, bufB, 1);

    // ---- conv3 ----
    gemm_mfma<128, 32, false><<<n / 64, 256, 0, stream>>>(bufB, w3h, w3l, nullptr, nullptr, bufA);
    agg32<<<n / 8, 256, 0, stream>>>(bufA, rowp, csrc, cwt, dis, b3, out);
}